// Round 8
// baseline (139.820 us; speedup 1.0000x reference)
//
#include <hip/hip_runtime.h>

#define BB 16
#define SS 2048
#define DD 64
#define OO 128
#define SPL 16
#define YEL (OO * DD)   // 8192 elems per Y[b]

typedef __attribute__((ext_vector_type(8))) short short8;   // 8 bf16 = 4 VGPRs
typedef __attribute__((ext_vector_type(4))) float f32x4;

__device__ __forceinline__ unsigned short f2bf(float f) {   // RNE fp32->bf16
    unsigned int u = __float_as_uint(f);
    return (unsigned short)((u + 0x7FFF + ((u >> 16) & 1)) >> 16);
}
__device__ __forceinline__ unsigned int pk2(float x, float y) {
    return (unsigned int)f2bf(x) | ((unsigned int)f2bf(y) << 16);
}
__device__ __forceinline__ short8 cvt8(float4 a, float4 b) {
    uint4 u = make_uint4(pk2(a.x, a.y), pk2(a.z, a.w), pk2(b.x, b.y), pk2(b.z, b.w));
    return *(short8*)&u;
}

// ---------------------------------------------------------------------------
// ONE worker dispatch (plus a 64B memset for cnt). grid = 256 x 512
// (1 block/CU -> all blocks co-resident -> per-batch polling is safe).
// Block (b = bx&15, p = bx>>4):
//  P1  (R5 k_yf body, 1x staging — no duplication): slab Yp[b*16+p][o][d] =
//      sum over 128-t slice of W[o,t]*X[b,t,d] via bf16 MFMA; X slice
//      transposed->bf16 in LDS (stride 132), W inline-cvt from global.
//  SYNC scope-16: syncthreads (drains vmcnt) + threadfence + atomicAdd(cnt[b]).
//      Last arriver (old==15) reduces 16 slabs -> YB[b] bf16 XOR-swizzled
//      (R6-verified layout), threadfence, cnt[b] += 256.
//  P3  after polling cnt[b]>=272: out[b, p*128.., :] = X @ Y^T + bias
//      (R6-verified math: B-frags uint4 direct from YB — L1-resident 16KB —
//       A-frags inline-cvt from X, direct stores). b's pipeline independently.
// ---------------------------------------------------------------------------
__global__ __launch_bounds__(512) void k_all2(const float* __restrict__ X,
                                              const float* __restrict__ W,
                                              const float* __restrict__ bias,
                                              float* __restrict__ out,
                                              float* __restrict__ Yp,
                                              unsigned short* __restrict__ YB,
                                              unsigned int* __restrict__ cnt) {
    __shared__ unsigned short XT[64 * 132];
    __shared__ unsigned int s_old;

    const int bx  = blockIdx.x;
    const int b   = bx & 15;
    const int p   = bx >> 4;
    const int tid = threadIdx.x;
    const int w   = tid >> 6;
    const int l   = tid & 63;
    const int n   = l & 15;
    const int q   = l >> 4;

    // ---------------- P1: split-K partial (R5 k_yf verbatim) ----------------
    {
        const int t0 = p * (SS / SPL);
        const float* Xb = X + ((size_t)b * SS + t0) * DD;
#pragma unroll
        for (int i = 0; i < 4; ++i) {
            const int tl = w * 4 + i * 32;
            const float x0 = Xb[(size_t)(tl + 0) * DD + l];
            const float x1 = Xb[(size_t)(tl + 1) * DD + l];
            const float x2 = Xb[(size_t)(tl + 2) * DD + l];
            const float x3 = Xb[(size_t)(tl + 3) * DD + l];
            *(uint2*)&XT[l * 132 + tl] = make_uint2(pk2(x0, x1), pk2(x2, x3));
        }
        __syncthreads();

        f32x4 acc[4];
#pragma unroll
        for (int j = 0; j < 4; ++j) acc[j] = {0.f, 0.f, 0.f, 0.f};

        const float* Wr = W + (size_t)(w * 16 + n) * SS + t0;
#pragma unroll
        for (int kk = 0; kk < SS / SPL; kk += 32) {
            const float4 wa = *(const float4*)(Wr + kk + q * 8);
            const float4 wb = *(const float4*)(Wr + kk + q * 8 + 4);
            const short8 a  = cvt8(wa, wb);
#pragma unroll
            for (int j = 0; j < 4; ++j) {
                const unsigned short* r = &XT[(j * 16 + n) * 132 + kk + q * 8];
                const uint2 lo = *(const uint2*)(r);
                const uint2 hi = *(const uint2*)(r + 4);
                uint4 u = make_uint4(lo.x, lo.y, hi.x, hi.y);
                acc[j] = __builtin_amdgcn_mfma_f32_16x16x32_bf16(a, *(short8*)&u, acc[j], 0, 0, 0);
            }
        }

        float* slab = Yp + (size_t)(b * SPL + p) * YEL;
#pragma unroll
        for (int j = 0; j < 4; ++j)
#pragma unroll
            for (int r = 0; r < 4; ++r)
                slab[(size_t)(w * 16 + q * 4 + r) * DD + j * 16 + n] = acc[j][r];
    }

    // ---------------- publish slab ----------------
    __syncthreads();                 // vmcnt(0) drain: slab stores in L2
    if (tid == 0) {
        __threadfence();             // device-scope release (cross-XCD safe)
        s_old = atomicAdd(&cnt[b], 1u);
    }
    __syncthreads();

    // ---------------- last arriver: reduce 16 slabs -> YB[b] ----------------
    if (s_old == SPL - 1) {
        __threadfence();             // acquire: invalidate caches before read
        const float* Yb0 = Yp + (size_t)b * SPL * YEL;
        unsigned short* YBb = YB + (size_t)b * YEL;
#pragma unroll
        for (int cidx = tid; cidx < 1024; cidx += 512) {  // 8-elem chunks
            const int o  = cidx >> 3;
            const int c8 = cidx & 7;
            const float* src = Yb0 + o * DD + c8 * 8;
            float4 s0v = {0.f, 0.f, 0.f, 0.f}, s1v = {0.f, 0.f, 0.f, 0.f};
#pragma unroll
            for (int pp = 0; pp < SPL; ++pp) {
                const float4 v0 = *(const float4*)(src + (size_t)pp * YEL);
                const float4 v1 = *(const float4*)(src + (size_t)pp * YEL + 4);
                s0v.x += v0.x; s0v.y += v0.y; s0v.z += v0.z; s0v.w += v0.w;
                s1v.x += v1.x; s1v.y += v1.y; s1v.z += v1.z; s1v.w += v1.w;
            }
            *(uint4*)(YBb + o * 64 + ((c8 ^ (o & 7)) << 3)) =
                make_uint4(pk2(s0v.x, s0v.y), pk2(s0v.z, s0v.w),
                           pk2(s1v.x, s1v.y), pk2(s1v.z, s1v.w));
        }
        __threadfence();             // release YB (flush to coherence point)
        __syncthreads();             // all reduce stores drained before flag
        if (tid == 0) atomicAdd(&cnt[b], 256u);
    }

    // ---------------- wait for YB[b] ----------------
    if (tid == 0) {
        while (__hip_atomic_load(&cnt[b], __ATOMIC_RELAXED,
                                 __HIP_MEMORY_SCOPE_AGENT) < SPL + 256u)
            __builtin_amdgcn_s_sleep(2);
    }
    __syncthreads();
    __threadfence();                 // acquire: fresh YB for all threads

    // ---------------- P3: out tile (R6-verified math) ----------------
    {
        const int s0 = p * 128;
        float bv[8];
#pragma unroll
        for (int j = 0; j < 8; ++j) bv[j] = bias[j * 16 + n];

        f32x4 acc[8];
#pragma unroll
        for (int j = 0; j < 8; ++j) acc[j] = {0.f, 0.f, 0.f, 0.f};

        const float*          Xr  = X  + ((size_t)b * SS + s0 + w * 16 + n) * DD;
        const unsigned short* YBb = YB + (size_t)b * YEL;

#pragma unroll
        for (int kk = 0; kk < DD; kk += 32) {
            const float4 xa = *(const float4*)(Xr + kk + q * 8);
            const float4 xb = *(const float4*)(Xr + kk + q * 8 + 4);
            const short8 a  = cvt8(xa, xb);
            const int c8    = (kk >> 3) + q;
#pragma unroll
            for (int j = 0; j < 8; ++j) {
                const int o = j * 16 + n;
                const uint4 u = *(const uint4*)(YBb + o * 64 + ((c8 ^ (o & 7)) << 3));
                acc[j] = __builtin_amdgcn_mfma_f32_16x16x32_bf16(a, *(short8*)&u, acc[j], 0, 0, 0);
            }
        }

        float* op = out + ((size_t)b * SS + s0 + w * 16 + q * 4) * OO;
#pragma unroll
        for (int j = 0; j < 8; ++j)
#pragma unroll
            for (int r = 0; r < 4; ++r)
                op[(size_t)r * OO + j * 16 + n] = acc[j][r] + bv[j];
    }
}

extern "C" void kernel_launch(void* const* d_in, const int* in_sizes, int n_in,
                              void* d_out, int out_size, void* d_ws, size_t ws_size,
                              hipStream_t stream) {
    const float* X    = (const float*)d_in[0];  // [B,S,D]
    const float* W    = (const float*)d_in[1];  // [OUT,S]
    const float* bias = (const float*)d_in[2];  // [OUT]
    float* out = (float*)d_out;                 // [B,S,OUT]

    unsigned int*   cnt = (unsigned int*)d_ws;                  // [16]
    float*          Yp  = (float*)((char*)d_ws + 256);          // [256][8192] fp32, 8.4MB
    unsigned short* YB  = (unsigned short*)(Yp + (size_t)BB * SPL * YEL);  // 256KB

    hipMemsetAsync(cnt, 0, BB * sizeof(unsigned int), stream);
    k_all2<<<dim3(256), dim3(512), 0, stream>>>(X, W, bias, out, Yp, YB, cnt);
}

// Round 9
// 76.933 us; speedup vs baseline: 1.8174x; 1.8174x over previous
//
#include <hip/hip_runtime.h>

#define BB 16
#define SS 2048
#define DD 64
#define OO 128
#define SPL 16
#define YEL (OO * DD)   // 8192 elems per Y[b] (and per slab)

typedef __attribute__((ext_vector_type(8))) short short8;   // 8 bf16 = 4 VGPRs
typedef __attribute__((ext_vector_type(4))) float f32x4;

__device__ __forceinline__ unsigned short f2bf(float f) {   // RNE fp32->bf16
    unsigned int u = __float_as_uint(f);
    return (unsigned short)((u + 0x7FFF + ((u >> 16) & 1)) >> 16);
}
__device__ __forceinline__ unsigned int pk2(float x, float y) {
    return (unsigned int)f2bf(x) | ((unsigned int)f2bf(y) << 16);
}
__device__ __forceinline__ short8 cvt8(float4 a, float4 b) {
    uint4 u = make_uint4(pk2(a.x, a.y), pk2(a.z, a.w), pk2(b.x, b.y), pk2(b.z, b.w));
    return *(short8*)&u;
}
__device__ __forceinline__ float bflo(unsigned int u) { return __uint_as_float(u << 16); }
__device__ __forceinline__ float bfhi(unsigned int u) { return __uint_as_float(u & 0xffff0000u); }

// swizzled element index within a Y[b] / slab: o in [0,128), d in [0,64)
__device__ __forceinline__ int yswz(int o, int d) {
    return (o << 6) + ((((d >> 3) ^ (o & 7)) << 3) | (d & 7));
}

// ---------------------------------------------------------------------------
// D1 k_yf (R5-verified body): slab[b][p] = partial Y over 128-t slice,
// stored as bf16 in the XOR-swizzled layout D2 consumes directly.
// grid 256 = (b = bx&15, p = bx>>4), 512 thr.
// ---------------------------------------------------------------------------
__global__ __launch_bounds__(512) void k_yf(const float* __restrict__ X,
                                            const float* __restrict__ W,
                                            unsigned short* __restrict__ YpB) {
    __shared__ unsigned short XT[64 * 132];

    const int bx  = blockIdx.x;
    const int b   = bx & 15;
    const int p   = bx >> 4;
    const int t0  = p * (SS / SPL);
    const int tid = threadIdx.x;
    const int w   = tid >> 6;
    const int l   = tid & 63;

    const float* Xb = X + ((size_t)b * SS + t0) * DD;
#pragma unroll
    for (int i = 0; i < 4; ++i) {
        const int tl = w * 4 + i * 32;
        const float x0 = Xb[(size_t)(tl + 0) * DD + l];
        const float x1 = Xb[(size_t)(tl + 1) * DD + l];
        const float x2 = Xb[(size_t)(tl + 2) * DD + l];
        const float x3 = Xb[(size_t)(tl + 3) * DD + l];
        *(uint2*)&XT[l * 132 + tl] = make_uint2(pk2(x0, x1), pk2(x2, x3));
    }
    __syncthreads();

    const int n = l & 15;
    const int q = l >> 4;

    f32x4 acc[4];
#pragma unroll
    for (int j = 0; j < 4; ++j) acc[j] = {0.f, 0.f, 0.f, 0.f};

    const float* Wr = W + (size_t)(w * 16 + n) * SS + t0;
#pragma unroll
    for (int kk = 0; kk < SS / SPL; kk += 32) {
        const float4 wa = *(const float4*)(Wr + kk + q * 8);
        const float4 wb = *(const float4*)(Wr + kk + q * 8 + 4);
        const short8 a  = cvt8(wa, wb);
#pragma unroll
        for (int j = 0; j < 4; ++j) {
            const unsigned short* r = &XT[(j * 16 + n) * 132 + kk + q * 8];
            const uint2 lo = *(const uint2*)(r);
            const uint2 hi = *(const uint2*)(r + 4);
            uint4 u = make_uint4(lo.x, lo.y, hi.x, hi.y);
            acc[j] = __builtin_amdgcn_mfma_f32_16x16x32_bf16(a, *(short8*)&u, acc[j], 0, 0, 0);
        }
    }

    unsigned short* slab = YpB + (size_t)(b * SPL + p) * YEL;
#pragma unroll
    for (int j = 0; j < 4; ++j)
#pragma unroll
        for (int r = 0; r < 4; ++r)
            slab[yswz(w * 16 + q * 4 + r, j * 16 + n)] = f2bf(acc[j][r]);
}

// ---------------------------------------------------------------------------
// D2 k_out2: per-block inline reduction of the 16 bf16 slabs -> YL (LDS,
// already-swizzled), then out[b, st*128.., :] = X @ Y^T + bias (R8-verified
// math; B-frags = conflict-free ds_read_b128 from YL, A inline-cvt from X).
// grid 256 = (b = bx&15, st = bx>>4), 512 thr.
// ---------------------------------------------------------------------------
__global__ __launch_bounds__(512) void k_out2(const float* __restrict__ X,
                                              const unsigned short* __restrict__ YpB,
                                              const float* __restrict__ bias,
                                              float* __restrict__ out) {
    __shared__ unsigned short YL[YEL];   // 16KB, swizzled bf16 Y[b]

    const int bx  = blockIdx.x;
    const int b   = bx & 15;
    const int st  = bx >> 4;
    const int tid = threadIdx.x;
    const int w   = tid >> 6;
    const int l   = tid & 63;
    const int n   = l & 15;
    const int q   = l >> 4;

    // ---- stage: reduce 16 slabs elementwise (coalesced uint4 chunks) ----
    const uint4* Yb4 = (const uint4*)(YpB + (size_t)b * SPL * YEL);
#pragma unroll
    for (int c = tid; c < YEL / 8; c += 512) {   // 2 chunks/thread
        float s[8];
#pragma unroll
        for (int e = 0; e < 8; ++e) s[e] = 0.f;
#pragma unroll
        for (int pp = 0; pp < SPL; ++pp) {
            const uint4 v = Yb4[(size_t)pp * (YEL / 8) + c];
            s[0] += bflo(v.x); s[1] += bfhi(v.x);
            s[2] += bflo(v.y); s[3] += bfhi(v.y);
            s[4] += bflo(v.z); s[5] += bfhi(v.z);
            s[6] += bflo(v.w); s[7] += bfhi(v.w);
        }
        ((uint4*)YL)[c] = make_uint4(pk2(s[0], s[1]), pk2(s[2], s[3]),
                                     pk2(s[4], s[5]), pk2(s[6], s[7]));
    }

    const int s0 = st * 128;
    float bv[8];
#pragma unroll
    for (int j = 0; j < 8; ++j) bv[j] = bias[j * 16 + n];

    f32x4 acc[8];
#pragma unroll
    for (int j = 0; j < 8; ++j) acc[j] = {0.f, 0.f, 0.f, 0.f};

    __syncthreads();

    // ---- P3: out tile (R8-verified math, B-frags from LDS) ----
    const float* Xr = X + ((size_t)b * SS + s0 + w * 16 + n) * DD;
#pragma unroll
    for (int kk = 0; kk < DD; kk += 32) {
        const float4 xa = *(const float4*)(Xr + kk + q * 8);
        const float4 xb = *(const float4*)(Xr + kk + q * 8 + 4);
        const short8 a  = cvt8(xa, xb);
        const int c8    = (kk >> 3) + q;
#pragma unroll
        for (int j = 0; j < 8; ++j) {
            const int o = j * 16 + n;
            const uint4 u = *(const uint4*)&YL[(o << 6) + (((c8 ^ (o & 7)) << 3))];
            acc[j] = __builtin_amdgcn_mfma_f32_16x16x32_bf16(a, *(short8*)&u, acc[j], 0, 0, 0);
        }
    }

    float* op = out + ((size_t)b * SS + s0 + w * 16 + q * 4) * OO;
#pragma unroll
    for (int j = 0; j < 8; ++j)
#pragma unroll
        for (int r = 0; r < 4; ++r)
            op[(size_t)r * OO + j * 16 + n] = acc[j][r] + bv[j];
}

extern "C" void kernel_launch(void* const* d_in, const int* in_sizes, int n_in,
                              void* d_out, int out_size, void* d_ws, size_t ws_size,
                              hipStream_t stream) {
    const float* X    = (const float*)d_in[0];  // [B,S,D]
    const float* W    = (const float*)d_in[1];  // [OUT,S]
    const float* bias = (const float*)d_in[2];  // [OUT]
    float* out = (float*)d_out;                 // [B,S,OUT]

    unsigned short* YpB = (unsigned short*)d_ws;   // [B*SPL][YEL] bf16 slabs, 4.2MB

    k_yf <<<dim3(256), dim3(512), 0, stream>>>(X, W, YpB);
    k_out2<<<dim3(256), dim3(512), 0, stream>>>(X, YpB, bias, out);
}